// Round 2
// baseline (11380.782 us; speedup 1.0000x reference)
//
#include <hip/hip_runtime.h>

// CTRNN fused, v2. B=512,T=1024,I=64,H=256,C=5, 6 unfolds of h=0.9h+0.1*tanh(xw+h@Wh).
// 32 wg x 256 thr (4 waves, 64 H-cols each). Transposed-MFMA form: a^T = Wh^T @ h^T
// (same resident fragments, args swapped) so C-layout gives 4 consecutive h-cols per
// lane -> b64 swizzled LDS writes. Counted-vmcnt barriers (lgkmcnt-only). xw(t+1) and
// logits(t-1) folded into unfold phases u=1/u=0.

#define T_ 1024
#define I_ 64
#define H_ 256
#define C_ 5

typedef float f32x4 __attribute__((ext_vector_type(4)));
typedef __bf16 bf16x8 __attribute__((ext_vector_type(8)));
typedef __bf16 bf16x4 __attribute__((ext_vector_type(4)));
typedef unsigned short ushort_t;
typedef ushort_t ushort8 __attribute__((ext_vector_type(8)));

__device__ __forceinline__ ushort_t f2bf(float x) {
  unsigned u = __builtin_bit_cast(unsigned, x);
  return (ushort_t)((u + 0x7FFFu + ((u >> 16) & 1u)) >> 16);  // RNE (setup only)
}
// lgkmcnt-only barrier: LDS writes visible, vmcnt (global prefetch/stores) stays in flight.
__device__ __forceinline__ void bar_lds() {
  asm volatile("s_waitcnt lgkmcnt(0)" ::: "memory");
  __builtin_amdgcn_s_barrier();
  asm volatile("" ::: "memory");
}
#define MFMA(a, b, c) __builtin_amdgcn_mfma_f32_16x16x32_bf16((a), (b), (c), 0, 0, 0)

__launch_bounds__(256, 1)
__global__ void ctrnn_fused(const float* __restrict__ x, const float* __restrict__ W,
                            const float* __restrict__ bh, const float* __restrict__ Wfc,
                            const float* __restrict__ bfc, float* __restrict__ out) {
  __shared__ __align__(16) char hbuf[2][16 * 256 * 2];  // h[b][j] bf16, swizzled
  __shared__ __align__(16) char xls[16 * 64 * 2];
  __shared__ float red[4][16][C_ + 1];

  const int tid = threadIdx.x;
  const int w   = tid >> 6;
  const int l   = tid & 63;
  const int lr  = l & 15;
  const int lq  = l >> 4;
  const int b0  = blockIdx.x << 4;

  // ---- resident fragments (identical load pattern to v1) ----
  bf16x8 wh[8][4];   // Wh[32kt+8lq+j][64w+16s+lr]
  bf16x8 wx[2][4];
  bf16x8 wf[2];
#pragma unroll
  for (int kt = 0; kt < 8; ++kt)
#pragma unroll
    for (int s = 0; s < 4; ++s) {
      ushort8 tmp;
#pragma unroll
      for (int j = 0; j < 8; ++j) {
        int k = kt * 32 + lq * 8 + j;
        int col = w * 64 + s * 16 + lr;
        tmp[j] = f2bf(W[(size_t)(I_ + k) * H_ + col]);
      }
      wh[kt][s] = __builtin_bit_cast(bf16x8, tmp);
    }
#pragma unroll
  for (int kt = 0; kt < 2; ++kt)
#pragma unroll
    for (int s = 0; s < 4; ++s) {
      ushort8 tmp;
#pragma unroll
      for (int j = 0; j < 8; ++j) {
        int k = kt * 32 + lq * 8 + j;
        int col = w * 64 + s * 16 + lr;
        tmp[j] = f2bf(W[(size_t)k * H_ + col]);
      }
      wx[kt][s] = __builtin_bit_cast(bf16x8, tmp);
    }
#pragma unroll
  for (int kt = 0; kt < 2; ++kt) {
    ushort8 tmp;
#pragma unroll
    for (int j = 0; j < 8; ++j) {
      int k = w * 64 + kt * 32 + lq * 8 + j;
      tmp[j] = (lr < C_) ? f2bf(Wfc[(size_t)k * C_ + lr]) : (ushort_t)0;
    }
    wf[kt] = __builtin_bit_cast(bf16x8, tmp);
  }
  // bias: acc rows are j = 64w+16s+4lq+jj -> per-lane float4
  float4 bia4[4];
#pragma unroll
  for (int s = 0; s < 4; ++s)
    bia4[s] = *(const float4*)(bh + w * 64 + s * 16 + lq * 4);

  // zero h(−1) buffer
  ((uint4*)hbuf[0])[tid]       = (uint4){0, 0, 0, 0};
  ((uint4*)hbuf[0])[tid + 256] = (uint4){0, 0, 0, 0};

  // stage x(0)
  const int xrow = tid >> 4, xc = tid & 15;
  const float* xbase = x + (size_t)(b0 + xrow) * T_ * I_ + xc * 4;
  float4 xp = *(const float4*)(xbase);
  {
    int byte = xrow * 128 + xc * 8;
    byte ^= (xrow & 7) << 4;
    bf16x4 pk = {(__bf16)xp.x, (__bf16)xp.y, (__bf16)xp.z, (__bf16)xp.w};
    *(bf16x4*)(xls + byte) = pk;
  }
  bar_lds();

  // xw(0) = (x0 @ Wx + b)^T via MFMA(wx, xa)
  f32x4 xw[4];
  {
    bf16x8 xa[2];
#pragma unroll
    for (int kt = 0; kt < 2; ++kt) {
      int byte = lr * 128 + (kt * 32 + lq * 8) * 2;
      byte ^= (lr & 7) << 4;
      xa[kt] = *(const bf16x8*)(xls + byte);
    }
#pragma unroll
    for (int s = 0; s < 4; ++s) {
      f32x4 a = (f32x4){bia4[s].x, bia4[s].y, bia4[s].z, bia4[s].w};
      a = MFMA(wx[0][s], xa[0], a);
      a = MFMA(wx[1][s], xa[1], a);
      xw[s] = a;
    }
  }
  xp = *(const float4*)(xbase + I_);  // x(1)

  f32x4 h[4];
#pragma unroll
  for (int s = 0; s < 4; ++s) h[s] = (f32x4){0.f, 0.f, 0.f, 0.f};

  const bool ow = tid < 16 * C_;
  int or_ = 0, oc_ = 0;
  float bfc_r = 0.f;
  if (ow) { or_ = tid / C_; oc_ = tid - or_ * C_; bfc_r = bfc[oc_]; }

#pragma unroll 1
  for (int t = 0; t < T_; ++t) {
    f32x4 xwn[4];
#pragma unroll
    for (int u = 0; u < 6; ++u) {
      const char* hb = hbuf[u & 1];
      bf16x8 ha[8];
#pragma unroll
      for (int kt = 0; kt < 8; ++kt) {
        int byte = lr * 512 + (kt * 32 + lq * 8) * 2;
        byte ^= (lr & 7) << 4;
        ha[kt] = *(const bf16x8*)(hb + byte);
      }
      f32x4 acc[4];
#pragma unroll
      for (int s = 0; s < 4; ++s) acc[s] = xw[s];
#pragma unroll
      for (int kt = 0; kt < 8; ++kt)
#pragma unroll
        for (int s = 0; s < 4; ++s) acc[s] = MFMA(wh[kt][s], ha[kt], acc[s]);

      if (u == 0) {
        if (t > 0) {  // logits(t-1): h(t-1) == current ha
          f32x4 part = (f32x4){0.f, 0.f, 0.f, 0.f};
          part = MFMA(ha[2 * w], wf[0], part);
          part = MFMA(ha[2 * w + 1], wf[1], part);
          if (lr < C_) {
#pragma unroll
            for (int jj = 0; jj < 4; ++jj) red[w][lq * 4 + jj][lr] = part[jj];
          }
        }
        if (t + 1 < T_) {  // stage x(t+1)
          int byte = xrow * 128 + xc * 8;
          byte ^= (xrow & 7) << 4;
          bf16x4 pk = {(__bf16)xp.x, (__bf16)xp.y, (__bf16)xp.z, (__bf16)xp.w};
          *(bf16x4*)(xls + byte) = pk;
        }
      }
      if (u == 1) {
        if (t + 1 < T_) {  // xw(t+1)
          bf16x8 xa[2];
#pragma unroll
          for (int kt = 0; kt < 2; ++kt) {
            int byte = lr * 128 + (kt * 32 + lq * 8) * 2;
            byte ^= (lr & 7) << 4;
            xa[kt] = *(const bf16x8*)(xls + byte);
          }
#pragma unroll
          for (int s = 0; s < 4; ++s) {
            f32x4 a = (f32x4){bia4[s].x, bia4[s].y, bia4[s].z, bia4[s].w};
            a = MFMA(wx[0][s], xa[0], a);
            a = MFMA(wx[1][s], xa[1], a);
            xwn[s] = a;
          }
        }
        if (t > 0 && ow) {  // store logits(t-1)
          float sum = red[0][or_][oc_] + red[1][or_][oc_] + red[2][or_][oc_] +
                      red[3][or_][oc_] + bfc_r;
          out[((size_t)(b0 + or_) * C_ + oc_) * T_ + (t - 1)] = sum;
        }
        if (t + 2 < T_) xp = *(const float4*)(xbase + (size_t)(t + 2) * I_);
      }

      // tanh + state update + b64 swizzled write of h' (4 consecutive j per lane)
      char* hw = hbuf[(u + 1) & 1];
#pragma unroll
      for (int s = 0; s < 4; ++s) {
        f32x4 hv;
#pragma unroll
        for (int jj = 0; jj < 4; ++jj) {
          float v = acc[s][jj];
          float e = __expf(v + v);
          float r = __builtin_amdgcn_rcpf(e + 1.0f);
          float hn = __builtin_fmaf(-0.2f, r, __builtin_fmaf(0.9f, h[s][jj], 0.1f));
          h[s][jj] = hn;
          hv[jj] = hn;
        }
        int byte = lr * 512 + (w * 128 + s * 32 + lq * 8);
        byte ^= (lr & 7) << 4;
        bf16x4 pk = {(__bf16)hv[0], (__bf16)hv[1], (__bf16)hv[2], (__bf16)hv[3]};
        *(bf16x4*)(hw + byte) = pk;
      }
      bar_lds();
    }
    if (t + 1 < T_) {
#pragma unroll
      for (int s = 0; s < 4; ++s) xw[s] = xwn[s];
    }
  }

  // epilogue: logits for t = T-1 (h final is in hbuf[0])
  {
    bf16x8 hA0, hA1;
    int byte = lr * 512 + ((2 * w) * 32 + lq * 8) * 2;
    byte ^= (lr & 7) << 4;
    hA0 = *(const bf16x8*)(hbuf[0] + byte);
    byte = lr * 512 + ((2 * w + 1) * 32 + lq * 8) * 2;
    byte ^= (lr & 7) << 4;
    hA1 = *(const bf16x8*)(hbuf[0] + byte);
    f32x4 part = (f32x4){0.f, 0.f, 0.f, 0.f};
    part = MFMA(hA0, wf[0], part);
    part = MFMA(hA1, wf[1], part);
    if (lr < C_) {
#pragma unroll
      for (int jj = 0; jj < 4; ++jj) red[w][lq * 4 + jj][lr] = part[jj];
    }
  }
  bar_lds();
  if (ow) {
    float sum = red[0][or_][oc_] + red[1][or_][oc_] + red[2][or_][oc_] +
                red[3][or_][oc_] + bfc_r;
    out[((size_t)(b0 + or_) * C_ + oc_) * T_ + (T_ - 1)] = sum;
  }
}

extern "C" void kernel_launch(void* const* d_in, const int* in_sizes, int n_in,
                              void* d_out, int out_size, void* d_ws, size_t ws_size,
                              hipStream_t stream) {
  const float* x   = (const float*)d_in[0];
  const float* W   = (const float*)d_in[1];
  const float* bh  = (const float*)d_in[2];
  const float* Wfc = (const float*)d_in[3];
  const float* bfc = (const float*)d_in[4];
  float* out = (float*)d_out;
  (void)in_sizes; (void)n_in; (void)out_size; (void)d_ws; (void)ws_size;
  ctrnn_fused<<<dim3(32), dim3(256), 0, stream>>>(x, W, bh, Wfc, bfc, out);
}

// Round 3
// 11302.391 us; speedup vs baseline: 1.0069x; 1.0069x over previous
//
#include <hip/hip_runtime.h>

// CTRNN fused, v3 = v1 structure with 2 independent 16-row streams per workgroup.
// 16 wgs x 512 threads (8 waves, 2/SIMD). Wave w: row-half = w>>2, col-group = w&3.
// Inner mechanics identical to v1 (MFMA(ha, wh), scalar b16 h-writes, __syncthreads).

#define T_ 1024
#define I_ 64
#define H_ 256
#define C_ 5

typedef float f32x4 __attribute__((ext_vector_type(4)));
typedef __bf16 bf16x8 __attribute__((ext_vector_type(8)));
typedef unsigned short ushort_t;
typedef ushort_t ushort8 __attribute__((ext_vector_type(8)));

__device__ __forceinline__ ushort_t f2bf(float x) {
  unsigned u = __builtin_bit_cast(unsigned, x);
  return (ushort_t)((u + 0x7FFFu + ((u >> 16) & 1u)) >> 16);  // RNE
}
#define MFMA(a, b, c) __builtin_amdgcn_mfma_f32_16x16x32_bf16((a), (b), (c), 0, 0, 0)

__launch_bounds__(512, 2)
__global__ void ctrnn_fused(const float* __restrict__ x, const float* __restrict__ W,
                            const float* __restrict__ bh, const float* __restrict__ Wfc,
                            const float* __restrict__ bfc, float* __restrict__ out) {
  // h ping-pong: [2][32 rows][256 cols] bf16, swizzled byte^=(row&7)<<4
  __shared__ __align__(16) char hbuf[2][32 * 256 * 2];
  __shared__ __align__(16) char xls[32 * 64 * 2];
  __shared__ float red[8][16][C_];

  const int tid  = threadIdx.x;
  const int w    = tid >> 6;
  const int l    = tid & 63;
  const int lr   = l & 15;
  const int lq   = l >> 4;
  const int half = w >> 2;      // row-half 0/1
  const int cg   = w & 3;       // col-group 0..3
  const int rb   = half * 16;   // row base within wg
  const int b0   = blockIdx.x << 5;

  // ---- resident fragments ----
  bf16x8 wh[8][4];   // Wh[32kt+8lq+j][64cg+16s+lr]
  bf16x8 wx[2][4];
  bf16x8 wf[2];
  float bia[4];

#pragma unroll
  for (int kt = 0; kt < 8; ++kt)
#pragma unroll
    for (int s = 0; s < 4; ++s) {
      ushort8 tmp;
#pragma unroll
      for (int j = 0; j < 8; ++j) {
        int k = kt * 32 + lq * 8 + j;
        int col = cg * 64 + s * 16 + lr;
        tmp[j] = f2bf(W[(size_t)(I_ + k) * H_ + col]);
      }
      wh[kt][s] = __builtin_bit_cast(bf16x8, tmp);
    }
#pragma unroll
  for (int kt = 0; kt < 2; ++kt)
#pragma unroll
    for (int s = 0; s < 4; ++s) {
      ushort8 tmp;
#pragma unroll
      for (int j = 0; j < 8; ++j) {
        int k = kt * 32 + lq * 8 + j;
        int col = cg * 64 + s * 16 + lr;
        tmp[j] = f2bf(W[(size_t)k * H_ + col]);
      }
      wx[kt][s] = __builtin_bit_cast(bf16x8, tmp);
    }
#pragma unroll
  for (int kt = 0; kt < 2; ++kt) {
    ushort8 tmp;
#pragma unroll
    for (int j = 0; j < 8; ++j) {
      int k = cg * 64 + kt * 32 + lq * 8 + j;
      tmp[j] = (lr < C_) ? f2bf(Wfc[(size_t)k * C_ + lr]) : (ushort_t)0;
    }
    wf[kt] = __builtin_bit_cast(bf16x8, tmp);
  }
#pragma unroll
  for (int s = 0; s < 4; ++s) bia[s] = bh[cg * 64 + s * 16 + lr];

  // zero h buffer 0 (16 KiB)
  ((uint4*)hbuf[0])[tid]       = (uint4){0, 0, 0, 0};
  ((uint4*)hbuf[0])[tid + 512] = (uint4){0, 0, 0, 0};

  // x prefetch for t=0: 512 threads -> (row=tid>>4 in 0..31, float4 chunk=tid&15)
  const int xrow = tid >> 4, xc = tid & 15;
  const float* xbase = x + (size_t)(b0 + xrow) * T_ * I_ + xc * 4;
  float4 xpre = *(const float4*)(xbase);

  __syncthreads();

  f32x4 h[4];  // fp32 state: rows rb+lq*4+jj, cols 64cg+16s+lr
#pragma unroll
  for (int s = 0; s < 4; ++s) h[s] = (f32x4){0.f, 0.f, 0.f, 0.f};

#pragma unroll 1
  for (int t = 0; t < T_; ++t) {
    // ---- stage x tile (32x64 bf16, swizzled) ----
    {
      int byte = xrow * 128 + xc * 8;
      byte ^= (xrow & 7) << 4;
      uint2 pk;
      pk.x = (unsigned)f2bf(xpre.x) | ((unsigned)f2bf(xpre.y) << 16);
      pk.y = (unsigned)f2bf(xpre.z) | ((unsigned)f2bf(xpre.w) << 16);
      *(uint2*)(xls + byte) = pk;
    }
    __syncthreads();

    // ---- xw = x @ Wx + b ----
    f32x4 xw[4];
    {
      bf16x8 xa[2];
#pragma unroll
      for (int kt = 0; kt < 2; ++kt) {
        int byte = (rb + lr) * 128 + (kt * 32 + lq * 8) * 2;
        byte ^= (lr & 7) << 4;
        xa[kt] = *(const bf16x8*)(xls + byte);
      }
#pragma unroll
      for (int s = 0; s < 4; ++s) {
        f32x4 a = (f32x4){bia[s], bia[s], bia[s], bia[s]};
        a = MFMA(xa[0], wx[0][s], a);
        a = MFMA(xa[1], wx[1][s], a);
        xw[s] = a;
      }
    }
    if (t + 1 < T_) xpre = *(const float4*)(xbase + (size_t)(t + 1) * I_);

    // ---- 6 unfolds ----
#pragma unroll
    for (int u = 0; u < 6; ++u) {
      const char* hb = hbuf[u & 1];
      bf16x8 ha[8];
#pragma unroll
      for (int kt = 0; kt < 8; ++kt) {
        int byte = (rb + lr) * 512 + (kt * 32 + lq * 8) * 2;
        byte ^= (lr & 7) << 4;
        ha[kt] = *(const bf16x8*)(hb + byte);
      }
      f32x4 acc[4];
#pragma unroll
      for (int s = 0; s < 4; ++s) acc[s] = xw[s];
#pragma unroll
      for (int kt = 0; kt < 8; ++kt)
#pragma unroll
        for (int s = 0; s < 4; ++s) acc[s] = MFMA(ha[kt], wh[kt][s], acc[s]);

      char* hw = hbuf[(u + 1) & 1];
#pragma unroll
      for (int s = 0; s < 4; ++s)
#pragma unroll
        for (int jj = 0; jj < 4; ++jj) {
          float v = acc[s][jj];
          float e = __expf(v + v);
          float f = 1.0f - 2.0f * __builtin_amdgcn_rcpf(e + 1.0f);
          float hn = 0.9f * h[s][jj] + 0.1f * f;
          h[s][jj] = hn;
          int row = rb + lq * 4 + jj, col = cg * 64 + s * 16 + lr;
          int byte = row * 512 + col * 2;
          byte ^= (row & 7) << 4;
          *(ushort_t*)(hw + byte) = f2bf(hn);
        }
      __syncthreads();
    }

    // ---- logits: wave (half,cg) does K chunk [64cg, 64cg+64) of its half ----
    {
      bf16x8 hA0, hA1;
      int byte = (rb + lr) * 512 + ((2 * cg) * 32 + lq * 8) * 2;
      byte ^= (lr & 7) << 4;
      hA0 = *(const bf16x8*)(hbuf[0] + byte);
      byte = (rb + lr) * 512 + ((2 * cg + 1) * 32 + lq * 8) * 2;
      byte ^= (lr & 7) << 4;
      hA1 = *(const bf16x8*)(hbuf[0] + byte);
      f32x4 part = (f32x4){0.f, 0.f, 0.f, 0.f};
      part = MFMA(hA0, wf[0], part);
      part = MFMA(hA1, wf[1], part);
      if (lr < C_) {
#pragma unroll
        for (int jj = 0; jj < 4; ++jj) red[w][lq * 4 + jj][lr] = part[jj];
      }
    }
    __syncthreads();
    if (tid < 32 * C_) {
      int r = tid / C_, c = tid - r * C_;
      int hb4 = (r >> 4) << 2, rl = r & 15;
      float sum = red[hb4 + 0][rl][c] + red[hb4 + 1][rl][c] + red[hb4 + 2][rl][c] +
                  red[hb4 + 3][rl][c] + bfc[c];
      out[((size_t)(b0 + r) * C_ + c) * T_ + t] = sum;
    }
    // next writers of red/xls are >=7 barriers away
  }
}

extern "C" void kernel_launch(void* const* d_in, const int* in_sizes, int n_in,
                              void* d_out, int out_size, void* d_ws, size_t ws_size,
                              hipStream_t stream) {
  const float* x   = (const float*)d_in[0];
  const float* W   = (const float*)d_in[1];
  const float* bh  = (const float*)d_in[2];
  const float* Wfc = (const float*)d_in[3];
  const float* bfc = (const float*)d_in[4];
  float* out = (float*)d_out;
  (void)in_sizes; (void)n_in; (void)out_size; (void)d_ws; (void)ws_size;
  ctrnn_fused<<<dim3(16), dim3(512), 0, stream>>>(x, W, bh, Wfc, bfc, out);
}

// Round 5
// 4183.583 us; speedup vs baseline: 2.7203x; 2.7016x over previous
//
#include <hip/hip_runtime.h>

// CTRNN fused, v4 = v1 phase structure + transposed MFMA core.
// 32 wgs x 256 thr (4 waves). a^T = Wh^T @ h^T via MFMA(wh_frag, ha_frag):
// each lane owns 4 consecutive H-cols of one batch row -> b64 LDS writes +
// cvt_pk bf16 packs. Plain __syncthreads everywhere; xw and logits are
// separate phases exactly as v1; x-staging rides u=5's barrier (7 barriers/t).

#define T_ 1024
#define I_ 64
#define H_ 256
#define C_ 5

typedef float f32x4 __attribute__((ext_vector_type(4)));
typedef __bf16 bf16x8 __attribute__((ext_vector_type(8)));
typedef __bf16 bf16x4 __attribute__((ext_vector_type(4)));
typedef unsigned short ushort_t;
typedef ushort_t ushort8 __attribute__((ext_vector_type(8)));

__device__ __forceinline__ ushort_t f2bf(float x) {  // setup only
  unsigned u = __builtin_bit_cast(unsigned, x);
  return (ushort_t)((u + 0x7FFFu + ((u >> 16) & 1u)) >> 16);
}
#define MFMA(a, b, c) __builtin_amdgcn_mfma_f32_16x16x32_bf16((a), (b), (c), 0, 0, 0)

__launch_bounds__(256, 1)
__global__ void ctrnn_fused(const float* __restrict__ x, const float* __restrict__ W,
                            const float* __restrict__ bh, const float* __restrict__ Wfc,
                            const float* __restrict__ bfc, float* __restrict__ out) {
  // h ping-pong [2][16 batch rows][256 H-cols] bf16, swizzle byte^=(row&7)<<4
  __shared__ __align__(16) char hbuf[2][16 * 256 * 2];
  __shared__ __align__(16) char xls[16 * 64 * 2];
  __shared__ float red[4][16][C_];

  const int tid = threadIdx.x;
  const int cg  = tid >> 6;   // wave = H col-group, owns cols [64cg, 64cg+64)
  const int l   = tid & 63;
  const int lr  = l & 15;
  const int lq  = l >> 4;
  const int b0  = blockIdx.x << 4;

  // ---- resident fragments (same data layout as v1) ----
  bf16x8 wh[8][4];   // Wh[32kt+8lq+j][64cg+16s+lr] : used as MFMA A (m=H-col)
  bf16x8 wx[2][4];
  bf16x8 wf[2];
#pragma unroll
  for (int kt = 0; kt < 8; ++kt)
#pragma unroll
    for (int s = 0; s < 4; ++s) {
      ushort8 tmp;
#pragma unroll
      for (int j = 0; j < 8; ++j) {
        int k = kt * 32 + lq * 8 + j;
        int col = cg * 64 + s * 16 + lr;
        tmp[j] = f2bf(W[(size_t)(I_ + k) * H_ + col]);
      }
      wh[kt][s] = __builtin_bit_cast(bf16x8, tmp);
    }
#pragma unroll
  for (int kt = 0; kt < 2; ++kt)
#pragma unroll
    for (int s = 0; s < 4; ++s) {
      ushort8 tmp;
#pragma unroll
      for (int j = 0; j < 8; ++j) {
        int k = kt * 32 + lq * 8 + j;
        int col = cg * 64 + s * 16 + lr;
        tmp[j] = f2bf(W[(size_t)k * H_ + col]);
      }
      wx[kt][s] = __builtin_bit_cast(bf16x8, tmp);
    }
#pragma unroll
  for (int kt = 0; kt < 2; ++kt) {
    ushort8 tmp;
#pragma unroll
    for (int j = 0; j < 8; ++j) {
      int k = cg * 64 + kt * 32 + lq * 8 + j;
      tmp[j] = (lr < C_) ? f2bf(Wfc[(size_t)k * C_ + lr]) : (ushort_t)0;
    }
    wf[kt] = __builtin_bit_cast(bf16x8, tmp);
  }
  // bias for transposed acc: rows are H-cols 64cg+16s+4lq+jj
  float4 bia4[4];
#pragma unroll
  for (int s = 0; s < 4; ++s) bia4[s] = *(const float4*)(bh + cg * 64 + s * 16 + lq * 4);

  // zero h(-1)
  ((uint4*)hbuf[0])[tid]       = (uint4){0, 0, 0, 0};
  ((uint4*)hbuf[0])[tid + 256] = (uint4){0, 0, 0, 0};

  // stage x(0) before the loop
  const int xrow = tid >> 4, xc = tid & 15;
  const float* xbase = x + (size_t)(b0 + xrow) * T_ * I_ + xc * 4;
  float4 xpre = *(const float4*)(xbase);
  {
    int byte = xrow * 128 + xc * 8;
    byte ^= (xrow & 7) << 4;
    bf16x4 pk = {(__bf16)xpre.x, (__bf16)xpre.y, (__bf16)xpre.z, (__bf16)xpre.w};
    *(bf16x4*)(xls + byte) = pk;
  }
  __syncthreads();

  f32x4 h[4];  // h[batch=lr][Hcol = 64cg+16s+4lq+jj]
#pragma unroll
  for (int s = 0; s < 4; ++s) h[s] = (f32x4){0.f, 0.f, 0.f, 0.f};

  const float TWO_LOG2E = 2.8853900817779268f;  // 2*log2(e)

#pragma unroll 1
  for (int t = 0; t < T_; ++t) {
    // ---- xw^T = Wx^T x^T + b : A=wx, B=xa ----
    f32x4 xw[4];
    {
      bf16x8 xa[2];
#pragma unroll
      for (int kt = 0; kt < 2; ++kt) {
        int byte = lr * 128 + (kt * 32 + lq * 8) * 2;
        byte ^= (lr & 7) << 4;
        xa[kt] = *(const bf16x8*)(xls + byte);
      }
#pragma unroll
      for (int s = 0; s < 4; ++s) {
        f32x4 a = (f32x4){bia4[s].x, bia4[s].y, bia4[s].z, bia4[s].w};
        a = MFMA(wx[0][s], xa[0], a);
        a = MFMA(wx[1][s], xa[1], a);
        xw[s] = a;
      }
    }
    if (t + 1 < T_) xpre = *(const float4*)(xbase + (size_t)(t + 1) * I_);

    // ---- 6 unfolds ----
#pragma unroll
    for (int u = 0; u < 6; ++u) {
      const char* hb = hbuf[u & 1];
      bf16x8 ha[8];  // B-frag: h[batch=lr][32kt+8lq+j]  (same reads as v1)
#pragma unroll
      for (int kt = 0; kt < 8; ++kt) {
        int byte = lr * 512 + (kt * 32 + lq * 8) * 2;
        byte ^= (lr & 7) << 4;
        ha[kt] = *(const bf16x8*)(hb + byte);
      }
      f32x4 acc[4];
#pragma unroll
      for (int s = 0; s < 4; ++s) acc[s] = xw[s];
#pragma unroll
      for (int kt = 0; kt < 8; ++kt)
#pragma unroll
        for (int s = 0; s < 4; ++s) acc[s] = MFMA(wh[kt][s], ha[kt], acc[s]);

      char* hw = hbuf[(u + 1) & 1];
#pragma unroll
      for (int s = 0; s < 4; ++s) {
        f32x4 hv;
#pragma unroll
        for (int jj = 0; jj < 4; ++jj) {
          float v = acc[s][jj];
          float e = __builtin_amdgcn_exp2f(v * TWO_LOG2E);   // e^{2v}
          float r = __builtin_amdgcn_rcpf(e + 1.0f);
          float hn = __builtin_fmaf(-0.2f, r, __builtin_fmaf(0.9f, h[s][jj], 0.1f));
          h[s][jj] = hn;
          hv[jj] = hn;
        }
        // 4 consecutive H-cols at batch row lr -> one b64 store
        int byte = lr * 512 + (cg * 128 + s * 32 + lq * 8);
        byte ^= (lr & 7) << 4;
        bf16x4 pk = {(__bf16)hv[0], (__bf16)hv[1], (__bf16)hv[2], (__bf16)hv[3]};
        *(bf16x4*)(hw + byte) = pk;
      }
      if (u == 5 && t + 1 < T_) {  // stage x(t+1), rides u=5's barrier
        int byte = xrow * 128 + xc * 8;
        byte ^= (xrow & 7) << 4;
        bf16x4 pk = {(__bf16)xpre.x, (__bf16)xpre.y, (__bf16)xpre.z, (__bf16)xpre.w};
        *(bf16x4*)(xls + byte) = pk;
      }
      __syncthreads();
    }

    // ---- logits (v1 pattern, reads hbuf[0] = h(t)) ----
    {
      bf16x8 hA0, hA1;
      int byte = lr * 512 + ((2 * cg) * 32 + lq * 8) * 2;
      byte ^= (lr & 7) << 4;
      hA0 = *(const bf16x8*)(hbuf[0] + byte);
      byte = lr * 512 + ((2 * cg + 1) * 32 + lq * 8) * 2;
      byte ^= (lr & 7) << 4;
      hA1 = *(const bf16x8*)(hbuf[0] + byte);
      f32x4 part = (f32x4){0.f, 0.f, 0.f, 0.f};
      part = MFMA(hA0, wf[0], part);
      part = MFMA(hA1, wf[1], part);
      if (lr < C_) {
#pragma unroll
        for (int jj = 0; jj < 4; ++jj) red[cg][lq * 4 + jj][lr] = part[jj];
      }
    }
    __syncthreads();
    if (tid < 16 * C_) {
      int r = tid / C_, c = tid - r * C_;
      float sum = red[0][r][c] + red[1][r][c] + red[2][r][c] + red[3][r][c] + bfc[c];
      out[((size_t)(b0 + r) * C_ + c) * T_ + t] = sum;
    }
    // next writers of red/xls are >=6 barriers away
  }
}

extern "C" void kernel_launch(void* const* d_in, const int* in_sizes, int n_in,
                              void* d_out, int out_size, void* d_ws, size_t ws_size,
                              hipStream_t stream) {
  const float* x   = (const float*)d_in[0];
  const float* W   = (const float*)d_in[1];
  const float* bh  = (const float*)d_in[2];
  const float* Wfc = (const float*)d_in[3];
  const float* bfc = (const float*)d_in[4];
  float* out = (float*)d_out;
  (void)in_sizes; (void)n_in; (void)out_size; (void)d_ws; (void)ws_size;
  ctrnn_fused<<<dim3(32), dim3(256), 0, stream>>>(x, W, bh, Wfc, bfc, out);
}

// Round 6
// 4119.908 us; speedup vs baseline: 2.7624x; 1.0155x over previous
//
#include <hip/hip_runtime.h>

// CTRNN fused, v5 = v4 + lgkmcnt-only barriers (pinned with sched_barrier, rule #18)
// + logits folded into peeled u=0 (6 barriers/t). Transposed MFMA core unchanged.

#define T_ 1024
#define I_ 64
#define H_ 256
#define C_ 5

typedef float f32x4 __attribute__((ext_vector_type(4)));
typedef __bf16 bf16x8 __attribute__((ext_vector_type(8)));
typedef __bf16 bf16x4 __attribute__((ext_vector_type(4)));
typedef unsigned short ushort_t;
typedef ushort_t ushort8 __attribute__((ext_vector_type(8)));

__device__ __forceinline__ ushort_t f2bf(float x) {  // setup only
  unsigned u = __builtin_bit_cast(unsigned, x);
  return (ushort_t)((u + 0x7FFFu + ((u >> 16) & 1u)) >> 16);
}
// LDS-only barrier: global prefetch/stores stay in flight across it.
__device__ __forceinline__ void bar_lds() {
  __builtin_amdgcn_sched_barrier(0);
  asm volatile("s_waitcnt lgkmcnt(0)" ::: "memory");
  __builtin_amdgcn_s_barrier();
  __builtin_amdgcn_sched_barrier(0);
}
#define MFMA(a, b, c) __builtin_amdgcn_mfma_f32_16x16x32_bf16((a), (b), (c), 0, 0, 0)

__launch_bounds__(256, 1)
__global__ void ctrnn_fused(const float* __restrict__ x, const float* __restrict__ W,
                            const float* __restrict__ bh, const float* __restrict__ Wfc,
                            const float* __restrict__ bfc, float* __restrict__ out) {
  __shared__ __align__(16) char hbuf[2][16 * 256 * 2];  // swizzle byte^=(row&7)<<4
  __shared__ __align__(16) char xls[16 * 64 * 2];
  __shared__ float red[4][16][C_];

  const int tid = threadIdx.x;
  const int cg  = tid >> 6;
  const int l   = tid & 63;
  const int lr  = l & 15;
  const int lq  = l >> 4;
  const int b0  = blockIdx.x << 4;

  // ---- resident fragments ----
  bf16x8 wh[8][4];
  bf16x8 wx[2][4];
  bf16x8 wf[2];
#pragma unroll
  for (int kt = 0; kt < 8; ++kt)
#pragma unroll
    for (int s = 0; s < 4; ++s) {
      ushort8 tmp;
#pragma unroll
      for (int j = 0; j < 8; ++j) {
        int k = kt * 32 + lq * 8 + j;
        int col = cg * 64 + s * 16 + lr;
        tmp[j] = f2bf(W[(size_t)(I_ + k) * H_ + col]);
      }
      wh[kt][s] = __builtin_bit_cast(bf16x8, tmp);
    }
#pragma unroll
  for (int kt = 0; kt < 2; ++kt)
#pragma unroll
    for (int s = 0; s < 4; ++s) {
      ushort8 tmp;
#pragma unroll
      for (int j = 0; j < 8; ++j) {
        int k = kt * 32 + lq * 8 + j;
        int col = cg * 64 + s * 16 + lr;
        tmp[j] = f2bf(W[(size_t)k * H_ + col]);
      }
      wx[kt][s] = __builtin_bit_cast(bf16x8, tmp);
    }
#pragma unroll
  for (int kt = 0; kt < 2; ++kt) {
    ushort8 tmp;
#pragma unroll
    for (int j = 0; j < 8; ++j) {
      int k = cg * 64 + kt * 32 + lq * 8 + j;
      tmp[j] = (lr < C_) ? f2bf(Wfc[(size_t)k * C_ + lr]) : (ushort_t)0;
    }
    wf[kt] = __builtin_bit_cast(bf16x8, tmp);
  }
  float4 bia4[4];
#pragma unroll
  for (int s = 0; s < 4; ++s) bia4[s] = *(const float4*)(bh + cg * 64 + s * 16 + lq * 4);

  ((uint4*)hbuf[0])[tid]       = (uint4){0, 0, 0, 0};
  ((uint4*)hbuf[0])[tid + 256] = (uint4){0, 0, 0, 0};

  const int xrow = tid >> 4, xc = tid & 15;
  const float* xbase = x + (size_t)(b0 + xrow) * T_ * I_ + xc * 4;
  float4 xpre = *(const float4*)(xbase);
  {
    int byte = xrow * 128 + xc * 8;
    byte ^= (xrow & 7) << 4;
    bf16x4 pk = {(__bf16)xpre.x, (__bf16)xpre.y, (__bf16)xpre.z, (__bf16)xpre.w};
    *(bf16x4*)(xls + byte) = pk;
  }
  __syncthreads();

  // xw(0)
  f32x4 xw[4];
  {
    bf16x8 xa[2];
#pragma unroll
    for (int kt = 0; kt < 2; ++kt) {
      int byte = lr * 128 + (kt * 32 + lq * 8) * 2;
      byte ^= (lr & 7) << 4;
      xa[kt] = *(const bf16x8*)(xls + byte);
    }
#pragma unroll
    for (int s = 0; s < 4; ++s) {
      f32x4 a = (f32x4){bia4[s].x, bia4[s].y, bia4[s].z, bia4[s].w};
      a = MFMA(wx[0][s], xa[0], a);
      a = MFMA(wx[1][s], xa[1], a);
      xw[s] = a;
    }
  }
  xpre = *(const float4*)(xbase + I_);

  f32x4 h[4];
#pragma unroll
  for (int s = 0; s < 4; ++s) h[s] = (f32x4){0.f, 0.f, 0.f, 0.f};

  const bool ow = tid < 16 * C_;
  int or_ = 0, oc_ = 0;
  float bfc_r = 0.f;
  if (ow) { or_ = tid / C_; oc_ = tid - or_ * C_; bfc_r = bfc[oc_]; }

  const float TWO_LOG2E = 2.8853900817779268f;

#pragma unroll 1
  for (int t = 0; t < T_; ++t) {
    // ================= u = 0 (peeled; + logits(t-1) MFMA & red-write) =========
    {
      const char* hb = hbuf[0];
      bf16x8 ha[8];
#pragma unroll
      for (int kt = 0; kt < 8; ++kt) {
        int byte = lr * 512 + (kt * 32 + lq * 8) * 2;
        byte ^= (lr & 7) << 4;
        ha[kt] = *(const bf16x8*)(hb + byte);
      }
      f32x4 part = (f32x4){0.f, 0.f, 0.f, 0.f};
      if (t > 0) {  // logits(t-1): h(t-1)-final == hbuf[0] right now
        bf16x8 hA0, hA1;
        int byte = lr * 512 + ((2 * cg) * 32 + lq * 8) * 2;
        byte ^= (lr & 7) << 4;
        hA0 = *(const bf16x8*)(hb + byte);
        byte = lr * 512 + ((2 * cg + 1) * 32 + lq * 8) * 2;
        byte ^= (lr & 7) << 4;
        hA1 = *(const bf16x8*)(hb + byte);
        part = MFMA(hA0, wf[0], part);
        part = MFMA(hA1, wf[1], part);
      }
      f32x4 acc[4];
#pragma unroll
      for (int s = 0; s < 4; ++s) acc[s] = xw[s];
#pragma unroll
      for (int kt = 0; kt < 8; ++kt)
#pragma unroll
        for (int s = 0; s < 4; ++s) acc[s] = MFMA(wh[kt][s], ha[kt], acc[s]);

      if (t > 0 && lr < C_) {
#pragma unroll
        for (int jj = 0; jj < 4; ++jj) red[cg][lq * 4 + jj][lr] = part[jj];
      }

      char* hw = hbuf[1];
#pragma unroll
      for (int s = 0; s < 4; ++s) {
        f32x4 hv;
#pragma unroll
        for (int jj = 0; jj < 4; ++jj) {
          float v = acc[s][jj];
          float e = __builtin_amdgcn_exp2f(v * TWO_LOG2E);
          float r = __builtin_amdgcn_rcpf(e + 1.0f);
          float hn = __builtin_fmaf(-0.2f, r, __builtin_fmaf(0.9f, h[s][jj], 0.1f));
          h[s][jj] = hn;
          hv[jj] = hn;
        }
        int byte = lr * 512 + (cg * 128 + s * 32 + lq * 8);
        byte ^= (lr & 7) << 4;
        bf16x4 pk = {(__bf16)hv[0], (__bf16)hv[1], (__bf16)hv[2], (__bf16)hv[3]};
        *(bf16x4*)(hw + byte) = pk;
      }
      bar_lds();
    }

    // ================= u = 1..5 =================
#pragma unroll
    for (int u = 1; u < 6; ++u) {
      const char* hb = hbuf[u & 1];
      bf16x8 ha[8];
#pragma unroll
      for (int kt = 0; kt < 8; ++kt) {
        int byte = lr * 512 + (kt * 32 + lq * 8) * 2;
        byte ^= (lr & 7) << 4;
        ha[kt] = *(const bf16x8*)(hb + byte);
      }
      f32x4 acc[4];
#pragma unroll
      for (int s = 0; s < 4; ++s) acc[s] = xw[s];
#pragma unroll
      for (int kt = 0; kt < 8; ++kt)
#pragma unroll
        for (int s = 0; s < 4; ++s) acc[s] = MFMA(wh[kt][s], ha[kt], acc[s]);

      if (u == 1 && t > 0 && ow) {  // store logits(t-1); red written before u=0's barrier
        float sum = red[0][or_][oc_] + red[1][or_][oc_] + red[2][or_][oc_] +
                    red[3][or_][oc_] + bfc_r;
        out[((size_t)(b0 + or_) * C_ + oc_) * T_ + (t - 1)] = sum;
      }

      char* hw = hbuf[(u + 1) & 1];
#pragma unroll
      for (int s = 0; s < 4; ++s) {
        f32x4 hv;
#pragma unroll
        for (int jj = 0; jj < 4; ++jj) {
          float v = acc[s][jj];
          float e = __builtin_amdgcn_exp2f(v * TWO_LOG2E);
          float r = __builtin_amdgcn_rcpf(e + 1.0f);
          float hn = __builtin_fmaf(-0.2f, r, __builtin_fmaf(0.9f, h[s][jj], 0.1f));
          h[s][jj] = hn;
          hv[jj] = hn;
        }
        int byte = lr * 512 + (cg * 128 + s * 32 + lq * 8);
        byte ^= (lr & 7) << 4;
        bf16x4 pk = {(__bf16)hv[0], (__bf16)hv[1], (__bf16)hv[2], (__bf16)hv[3]};
        *(bf16x4*)(hw + byte) = pk;
      }
      if (u == 5 && t + 1 < T_) {  // stage x(t+1), rides u=5's barrier
        int byte = xrow * 128 + xc * 8;
        byte ^= (xrow & 7) << 4;
        bf16x4 pk = {(__bf16)xpre.x, (__bf16)xpre.y, (__bf16)xpre.z, (__bf16)xpre.w};
        *(bf16x4*)(xls + byte) = pk;
      }
      bar_lds();
    }

    // ================= xw(t+1) — no barrier needed =================
    if (t + 1 < T_) {
      bf16x8 xa[2];
#pragma unroll
      for (int kt = 0; kt < 2; ++kt) {
        int byte = lr * 128 + (kt * 32 + lq * 8) * 2;
        byte ^= (lr & 7) << 4;
        xa[kt] = *(const bf16x8*)(xls + byte);
      }
#pragma unroll
      for (int s = 0; s < 4; ++s) {
        f32x4 a = (f32x4){bia4[s].x, bia4[s].y, bia4[s].z, bia4[s].w};
        a = MFMA(wx[0][s], xa[0], a);
        a = MFMA(wx[1][s], xa[1], a);
        xw[s] = a;
      }
      if (t + 2 < T_) xpre = *(const float4*)(xbase + (size_t)(t + 2) * I_);
    }
  }

  // ================= epilogue: logits(T-1) =================
  {
    const char* hb = hbuf[0];
    bf16x8 hA0, hA1;
    int byte = lr * 512 + ((2 * cg) * 32 + lq * 8) * 2;
    byte ^= (lr & 7) << 4;
    hA0 = *(const bf16x8*)(hb + byte);
    byte = lr * 512 + ((2 * cg + 1) * 32 + lq * 8) * 2;
    byte ^= (lr & 7) << 4;
    hA1 = *(const bf16x8*)(hb + byte);
    f32x4 part = (f32x4){0.f, 0.f, 0.f, 0.f};
    part = MFMA(hA0, wf[0], part);
    part = MFMA(hA1, wf[1], part);
    if (lr < C_) {
#pragma unroll
      for (int jj = 0; jj < 4; ++jj) red[cg][lq * 4 + jj][lr] = part[jj];
    }
  }
  bar_lds();
  if (ow) {
    float sum = red[0][or_][oc_] + red[1][or_][oc_] + red[2][or_][oc_] +
                red[3][or_][oc_] + bfc_r;
    out[((size_t)(b0 + or_) * C_ + oc_) * T_ + (T_ - 1)] = sum;
  }
}

extern "C" void kernel_launch(void* const* d_in, const int* in_sizes, int n_in,
                              void* d_out, int out_size, void* d_ws, size_t ws_size,
                              hipStream_t stream) {
  const float* x   = (const float*)d_in[0];
  const float* W   = (const float*)d_in[1];
  const float* bh  = (const float*)d_in[2];
  const float* Wfc = (const float*)d_in[3];
  const float* bfc = (const float*)d_in[4];
  float* out = (float*)d_out;
  (void)in_sizes; (void)n_in; (void)out_size; (void)d_ws; (void)ws_size;
  ctrnn_fused<<<dim3(32), dim3(256), 0, stream>>>(x, W, bh, Wfc, bfc, out);
}